// Round 1
// baseline (100.003 us; speedup 1.0000x reference)
//
#include <hip/hip_runtime.h>

// x (B=4, S=8192, D=2048) f32, filters (FO=2, B=4, S=8192, K=3) f32.
// out[b,t,c] = k[b,2]*x[b,t,c] + k[b,1]*x[b,t-1,c] + k[b,0]*x[b,t-2,c]
// k[b,j] = (1/S) * sum_{fo,s} filters[fo,b,s,j].

constexpr int B_ = 4;
constexpr int S_ = 8192;
constexpr int D_ = 2048;
constexpr int K_ = 3;
constexpr int TC = 32;          // t-chunk per conv block
constexpr int LD4 = D_ / 4;     // 512 float4 per row

typedef float f4 __attribute__((ext_vector_type(4)));

// ---------------- stage 1: parallel partial reduction of filters ----------
// 64 blocks: bid -> fo = bid>>5, b = (bid>>3)&3, slice = bid&7.
// Each block reads a contiguous 1024-s slice of one (fo,b) plane as 256
// groups of 3 float4 (= 4 complete K-triples); float j in a group has
// kk = j % 3 since all base offsets are divisible by 3.
__global__ __launch_bounds__(256) void reduce_partial_kernel(
    const float* __restrict__ filters, float* __restrict__ partials) {
    const int bid   = blockIdx.x;
    const int tid   = threadIdx.x;
    const int fo    = bid >> 5;
    const int b     = (bid >> 3) & 3;
    const int slice = bid & 7;

    const f4* F = (const f4*)filters;
    const int base_f4 = (fo * 4 + b) * 6144 + slice * 768;  // in float4 units

    const f4 a  = F[base_f4 + 3 * tid + 0];
    const f4 bb = F[base_f4 + 3 * tid + 1];
    const f4 c  = F[base_f4 + 3 * tid + 2];

    float s0 = a.x + a.w + bb.z + c.y;
    float s1 = a.y + bb.x + bb.w + c.z;
    float s2 = a.z + bb.y + c.x + c.w;

    __shared__ float red[3][256];
    red[0][tid] = s0; red[1][tid] = s1; red[2][tid] = s2;
    __syncthreads();
    for (int off = 128; off > 0; off >>= 1) {
        if (tid < off) {
            red[0][tid] += red[0][tid + off];
            red[1][tid] += red[1][tid + off];
            red[2][tid] += red[2][tid + off];
        }
        __syncthreads();
    }
    if (tid < 3) partials[bid * 3 + tid] = red[tid][0];
}

// ---------------- stage 2: causal conv, full-row blocks -------------------
// 512 threads/block, each thread owns exactly ONE channel-group (c4 = tid)
// register carry-pipeline across TC=32 t-steps. Same 1024 blocks / same
// bytes as before, but 8 waves/block -> 32 waves/CU (was 16): double the
// in-flight loads. Bijective XCD swizzle (1024 % 8 == 0) keeps t-adjacent
// chunks (which share halo rows + contiguous L3 lines) on one XCD's L2.
__global__ __launch_bounds__(512) void causal_conv_kernel(
    const float* __restrict__ x, const float* __restrict__ partials,
    float* __restrict__ out) {
    const int nchunk = S_ / TC;          // 256
    const int nwg    = B_ * nchunk;      // 1024
    // XCD-aware swizzle: hw round-robins blockIdx across 8 XCDs; remap so
    // each XCD owns a contiguous run of 128 logical chunks.
    const int raw = blockIdx.x;
    const int bid = (raw & 7) * (nwg >> 3) + (raw >> 3);

    const int tid    = threadIdx.x;      // 0..511 == c4 lane
    const int tchunk = bid % nchunk;
    const int b      = bid / nchunk;
    const int t0     = tchunk * TC;

    // fold the 16 partials (2 fo * 8 slices) for this batch
    __shared__ float ksh[3];
    if (tid < 3) {
        float s = 0.f;
        #pragma unroll
        for (int fo = 0; fo < 2; ++fo)
            #pragma unroll
            for (int sl = 0; sl < 8; ++sl)
                s += partials[(fo * 32 + b * 8 + sl) * 3 + tid];
        ksh[tid] = s * (1.0f / (float)S_);
    }
    __syncthreads();
    const float k0 = ksh[0], k1 = ksh[1], k2 = ksh[2];

    const f4* xb = (const f4*)x + (size_t)b * S_ * LD4;
    f4*       ob = (f4*)out     + (size_t)b * S_ * LD4;
    const int c4 = tid;                  // one full row per wave-burst set

    f4 z = (f4)(0.f);
    f4 am2 = (t0 >= 2) ? xb[(size_t)(t0 - 2) * LD4 + c4] : z;
    f4 am1 = (t0 >= 1) ? xb[(size_t)(t0 - 1) * LD4 + c4] : z;

    #pragma unroll
    for (int g = 0; g < TC / 4; ++g) {
        f4 xa[4];
        #pragma unroll
        for (int u = 0; u < 4; ++u) {
            const size_t t = (size_t)(t0 + g * 4 + u);
            xa[u] = xb[t * LD4 + c4];
        }
        #pragma unroll
        for (int u = 0; u < 4; ++u) {
            const size_t t = (size_t)(t0 + g * 4 + u);
            f4 oa = k2 * xa[u] + k1 * am1 + k0 * am2;
            __builtin_nontemporal_store(oa, &ob[t * LD4 + c4]);
            am2 = am1; am1 = xa[u];
        }
    }
}

extern "C" void kernel_launch(void* const* d_in, const int* in_sizes, int n_in,
                              void* d_out, int out_size, void* d_ws, size_t ws_size,
                              hipStream_t stream) {
    const float* x        = (const float*)d_in[0];
    const float* filters  = (const float*)d_in[1];
    float*       out      = (float*)d_out;
    float*       partials = (float*)d_ws;   // 64*3 = 192 floats

    reduce_partial_kernel<<<64, 256, 0, stream>>>(filters, partials);

    const int nblocks = B_ * (S_ / TC);  // 1024
    causal_conv_kernel<<<nblocks, 512, 0, stream>>>(x, partials, out);
}